// Round 1
// baseline (429.595 us; speedup 1.0000x reference)
//
#include <hip/hip_runtime.h>
#include <math.h>

#define N 8192
#define D 128
#define MARGIN 0.2f
#define PD_EPS 1e-6f
#define IMAX 0x7fffffff

// ---------------- kernel 1: row normalize + sq ----------------
__global__ __launch_bounds__(256) void k_normalize(const float* __restrict__ z,
                                                   float* __restrict__ zn,
                                                   float* __restrict__ sq) {
    int row  = blockIdx.x * 4 + (threadIdx.x >> 6);
    int lane = threadIdx.x & 63;
    float2 v = ((const float2*)(z + (size_t)row * D))[lane];
    float ss = v.x * v.x + v.y * v.y;
    #pragma unroll
    for (int m = 1; m < 64; m <<= 1) ss += __shfl_xor(ss, m, 64);
    float norm = fmaxf(sqrtf(ss), 1e-12f);
    float2 o;
    o.x = v.x / norm;
    o.y = v.y / norm;
    ((float2*)(zn + (size_t)row * D))[lane] = o;
    float s2 = o.x * o.x + o.y * o.y;
    #pragma unroll
    for (int m = 1; m < 64; m <<= 1) s2 += __shfl_xor(s2, m, 64);
    if (lane == 0) sq[row] = s2;
}

// ---------------- kernel 2: mining (tiled distance GEMM + argmax/argmin) ----
// Grid: (N/64 i-tiles, 4 j-chunks). Block 256 threads = 16x16, each thread
// owns a 4x4 (anchor x j) sub-tile. LDS holds A,B tiles transposed [k][row]
// with stride 68 so inner-loop reads are ds_read_b128 and ~conflict-free.
__global__ __launch_bounds__(256) void k_mine(const float* __restrict__ zn,
                                              const float* __restrict__ sq,
                                              const int* __restrict__ labels,
                                              const int* __restrict__ subjects,
                                              float* __restrict__ pmax, int* __restrict__ pidx,
                                              float* __restrict__ nmin, int* __restrict__ nidx) {
    __shared__ float As[D * 68];   // 34 KB  [k][i_local]
    __shared__ float Bs[D * 68];   // 34 KB  [k][j_local]
    __shared__ float sqj[64];
    __shared__ int   labj[64];
    __shared__ int   subjj[64];

    const int tid = threadIdx.x;
    const int tx = tid & 15, ty = tid >> 4;
    const int ibase  = blockIdx.x * 64;
    const int jstart = blockIdx.y * 2048;

    // stage A transposed (once per block)
    #pragma unroll
    for (int r = 0; r < 8; ++r) {
        int idx = tid + r * 256;      // 0..2047 float4 slots
        int row = idx >> 5;           // 0..63
        int c4  = idx & 31;           // 0..31
        float4 v = ((const float4*)(zn + (size_t)(ibase + row) * D))[c4];
        int k0 = c4 * 4;
        As[(k0 + 0) * 68 + row] = v.x;
        As[(k0 + 1) * 68 + row] = v.y;
        As[(k0 + 2) * 68 + row] = v.z;
        As[(k0 + 3) * 68 + row] = v.w;
    }

    float sqi[4]; int li[4], si[4];
    #pragma unroll
    for (int u = 0; u < 4; ++u) {
        int i = ibase + ty * 4 + u;
        sqi[u] = sq[i]; li[u] = labels[i]; si[u] = subjects[i];
    }

    float bpv[4], bnv[4]; int bpi[4], bni[4];
    #pragma unroll
    for (int u = 0; u < 4; ++u) {
        bpv[u] = -INFINITY; bnv[u] = INFINITY; bpi[u] = IMAX; bni[u] = IMAX;
    }

    for (int jt = 0; jt < 32; ++jt) {
        int jbase = jstart + jt * 64;
        __syncthreads();  // protect previous Bs readers (also orders As on iter 0)
        #pragma unroll
        for (int r = 0; r < 8; ++r) {
            int idx = tid + r * 256;
            int row = idx >> 5;
            int c4  = idx & 31;
            float4 v = ((const float4*)(zn + (size_t)(jbase + row) * D))[c4];
            int k0 = c4 * 4;
            Bs[(k0 + 0) * 68 + row] = v.x;
            Bs[(k0 + 1) * 68 + row] = v.y;
            Bs[(k0 + 2) * 68 + row] = v.z;
            Bs[(k0 + 3) * 68 + row] = v.w;
        }
        if (tid < 64) {
            sqj[tid]   = sq[jbase + tid];
            labj[tid]  = labels[jbase + tid];
            subjj[tid] = subjects[jbase + tid];
        }
        __syncthreads();

        float acc[4][4] = {};
        #pragma unroll 8
        for (int k = 0; k < D; ++k) {
            float4 a = *(const float4*)&As[k * 68 + ty * 4];
            float4 b = *(const float4*)&Bs[k * 68 + tx * 4];
            #pragma unroll
            for (int u = 0; u < 4; ++u) {
                float av = (u == 0) ? a.x : (u == 1) ? a.y : (u == 2) ? a.z : a.w;
                acc[u][0] = fmaf(av, b.x, acc[u][0]);
                acc[u][1] = fmaf(av, b.y, acc[u][1]);
                acc[u][2] = fmaf(av, b.z, acc[u][2]);
                acc[u][3] = fmaf(av, b.w, acc[u][3]);
            }
        }

        #pragma unroll
        for (int v = 0; v < 4; ++v) {
            int jj = tx * 4 + v;
            int j  = jbase + jj;
            float sj = sqj[jj];
            int lj = labj[jj], sb = subjj[jj];
            #pragma unroll
            for (int u = 0; u < 4; ++u) {
                float d2 = fmaxf((sqi[u] + sj) - 2.0f * acc[u][v], 0.0f);
                bool sc = (li[u] == lj), ssub = (si[u] == sb);
                if (sc && !ssub) {           // positive candidate (j==i excluded: same subject)
                    if (d2 > bpv[u] || (d2 == bpv[u] && j < bpi[u])) { bpv[u] = d2; bpi[u] = j; }
                } else if (!sc && ssub) {    // negative candidate (j==i excluded: same class)
                    if (d2 < bnv[u] || (d2 == bnv[u] && j < bni[u])) { bnv[u] = d2; bni[u] = j; }
                }
            }
        }
    }

    // reduce across the 16 tx-lanes sharing each ty (within-wave, xor<16)
    #pragma unroll
    for (int m = 1; m < 16; m <<= 1) {
        #pragma unroll
        for (int u = 0; u < 4; ++u) {
            float ov = __shfl_xor(bpv[u], m, 64);
            int   oi = __shfl_xor(bpi[u], m, 64);
            if (ov > bpv[u] || (ov == bpv[u] && oi < bpi[u])) { bpv[u] = ov; bpi[u] = oi; }
            float nv = __shfl_xor(bnv[u], m, 64);
            int   ni = __shfl_xor(bni[u], m, 64);
            if (nv < bnv[u] || (nv == bnv[u] && ni < bni[u])) { bnv[u] = nv; bni[u] = ni; }
        }
    }
    if (tx == 0) {
        #pragma unroll
        for (int u = 0; u < 4; ++u) {
            int i = ibase + ty * 4 + u;
            size_t o = (size_t)blockIdx.y * N + i;
            pmax[o] = bpv[u]; pidx[o] = bpi[u];
            nmin[o] = bnv[u]; nidx[o] = bni[u];
        }
    }
}

// ---------------- kernel 3: combine chunks + per-anchor hinge ----------------
__global__ __launch_bounds__(256) void k_final(const float* __restrict__ zn,
                                               const float* __restrict__ pmax, const int* __restrict__ pidx,
                                               const float* __restrict__ nmin, const int* __restrict__ nidx,
                                               float* __restrict__ per, float* __restrict__ vld) {
    int row  = blockIdx.x * 4 + (threadIdx.x >> 6);
    int lane = threadIdx.x & 63;
    float bpv = -INFINITY; int bpi = IMAX;
    float bnv =  INFINITY; int bni = IMAX;
    #pragma unroll
    for (int c = 0; c < 4; ++c) {
        float v = pmax[(size_t)c * N + row]; int ix = pidx[(size_t)c * N + row];
        if (v > bpv || (v == bpv && ix < bpi)) { bpv = v; bpi = ix; }
        float w = nmin[(size_t)c * N + row]; int jx = nidx[(size_t)c * N + row];
        if (w < bnv || (w == bnv && jx < bni)) { bnv = w; bni = jx; }
    }
    bool valid = (bpv != -INFINITY) && (bnv != INFINITY);
    int pi = valid ? bpi : 0;
    int ni = valid ? bni : 0;
    float2 a = ((const float2*)(zn + (size_t)row * D))[lane];
    float2 p = ((const float2*)(zn + (size_t)pi  * D))[lane];
    float2 n = ((const float2*)(zn + (size_t)ni  * D))[lane];
    float dx = a.x - p.x + PD_EPS, dy = a.y - p.y + PD_EPS;
    float sap = dx * dx + dy * dy;
    dx = a.x - n.x + PD_EPS; dy = a.y - n.y + PD_EPS;
    float san = dx * dx + dy * dy;
    #pragma unroll
    for (int m = 1; m < 64; m <<= 1) {
        sap += __shfl_xor(sap, m, 64);
        san += __shfl_xor(san, m, 64);
    }
    if (lane == 0) {
        float l = fmaxf(sqrtf(sap) - sqrtf(san) + MARGIN, 0.0f);
        per[row] = valid ? l : 0.0f;
        vld[row] = valid ? 1.0f : 0.0f;
    }
}

// ---------------- kernel 4: deterministic final reduce ----------------
__global__ __launch_bounds__(256) void k_reduce(const float* __restrict__ per,
                                                const float* __restrict__ vld,
                                                float* __restrict__ out) {
    __shared__ float s1[256], s2[256];
    int t = threadIdx.x;
    float a = 0.f, b = 0.f;
    for (int i = t; i < N; i += 256) { a += per[i]; b += vld[i]; }
    s1[t] = a; s2[t] = b;
    __syncthreads();
    for (int w = 128; w > 0; w >>= 1) {
        if (t < w) { s1[t] += s1[t + w]; s2[t] += s2[t + w]; }
        __syncthreads();
    }
    if (t == 0) {
        float cnt = s2[0];
        float loss = (cnt > 0.f) ? s1[0] / fmaxf(cnt, 1.f) : 0.f;
        out[0] = loss;   // W_HARD=1, denom=1
    }
}

extern "C" void kernel_launch(void* const* d_in, const int* in_sizes, int n_in,
                              void* d_out, int out_size, void* d_ws, size_t ws_size,
                              hipStream_t stream) {
    const float* z        = (const float*)d_in[0];
    const int*   labels   = (const int*)d_in[1];
    const int*   subjects = (const int*)d_in[2];
    float* out = (float*)d_out;

    char* ws = (char*)d_ws;
    float* zn   = (float*)(ws);                          // 4 MB
    float* sq   = (float*)(ws + 4194304);                // 32 KB
    float* pmax = (float*)(ws + 4227072);                // 128 KB
    int*   pidx = (int*)  (ws + 4358144);                // 128 KB
    float* nmin = (float*)(ws + 4489216);                // 128 KB
    int*   nidx = (int*)  (ws + 4620288);                // 128 KB
    float* per  = (float*)(ws + 4751360);                // 32 KB
    float* vld  = (float*)(ws + 4784128);                // 32 KB

    k_normalize<<<dim3(N / 4), dim3(256), 0, stream>>>(z, zn, sq);
    k_mine<<<dim3(N / 64, 4), dim3(256), 0, stream>>>(zn, sq, labels, subjects,
                                                      pmax, pidx, nmin, nidx);
    k_final<<<dim3(N / 4), dim3(256), 0, stream>>>(zn, pmax, pidx, nmin, nidx, per, vld);
    k_reduce<<<dim3(1), dim3(256), 0, stream>>>(per, vld, out);
}

// Round 2
// 116.094 us; speedup vs baseline: 3.7004x; 3.7004x over previous
//
#include <hip/hip_runtime.h>
#include <math.h>

#define N 8192
#define D 128
#define MARGIN 0.2f
#define PD_EPS 1e-6f
#define NCHUNK 16
#define CHUNKJ (N / NCHUNK)   // 512 j per chunk

typedef __attribute__((ext_vector_type(8))) short bf16x8;  // 8 bf16 = 4 VGPRs
typedef __attribute__((ext_vector_type(4))) float f32x4;

__device__ __forceinline__ unsigned short f2bf(float f) {
    unsigned u = __float_as_uint(f);
    u += 0x7FFFu + ((u >> 16) & 1u);   // round-to-nearest-even
    return (unsigned short)(u >> 16);
}
__device__ __forceinline__ unsigned umn(unsigned a, unsigned b) { return a < b ? a : b; }
__device__ __forceinline__ unsigned umx(unsigned a, unsigned b) { return a > b ? a : b; }

// ---------------- kernel 1: normalize -> bf16 rows + inv-norm + packed meta ---
__global__ __launch_bounds__(256) void k_normalize(const float* __restrict__ z,
                                                   const int* __restrict__ labels,
                                                   const int* __restrict__ subjects,
                                                   unsigned short* __restrict__ znb,
                                                   float* __restrict__ invn,
                                                   int* __restrict__ meta) {
    int row  = blockIdx.x * 4 + (threadIdx.x >> 6);
    int lane = threadIdx.x & 63;
    float2 v = ((const float2*)(z + (size_t)row * D))[lane];
    float ss = v.x * v.x + v.y * v.y;
    #pragma unroll
    for (int m = 1; m < 64; m <<= 1) ss += __shfl_xor(ss, m, 64);
    float norm = fmaxf(sqrtf(ss), 1e-12f);
    float ox = v.x / norm, oy = v.y / norm;
    ushort2 b; b.x = f2bf(ox); b.y = f2bf(oy);
    ((ushort2*)(znb + (size_t)row * D))[lane] = b;
    if (lane == 0) {
        invn[row] = 1.0f / norm;
        meta[row] = labels[row] * 32 + subjects[row];   // 9 bits: label(4)|subject(5)
    }
}

// ---------------- kernel 2: MFMA mining --------------------------------------
// Wave owns 64 anchors (4 utiles of 16x16x32 MFMA); sweeps CHUNKJ js in 64-wide
// tiles. Since rows are unit-norm, hardest-pos = min dot, hardest-neg = max dot.
// Key = (bits(dot+2) & ~8191) | j  -> min/max carries the argindex.
__global__ __launch_bounds__(256, 2) void k_mine(const unsigned short* __restrict__ znb,
                                                 const int* __restrict__ meta,
                                                 unsigned* __restrict__ posk,
                                                 unsigned* __restrict__ negk) {
    const int wave = threadIdx.x >> 6;
    const int lane = threadIdx.x & 63;
    const int m    = lane & 15;     // A/B operand row within 16-tile
    const int quad = lane >> 4;     // k-half selector / C-row group
    const int iw   = (blockIdx.x * 4 + wave) * 64;
    const int jc   = blockIdx.y;
    const int jbase = jc * CHUNKJ;

    // persistent A fragments: [utile][kstep], lane holds row iw+u*16+m,
    // k = s*32 + quad*8 .. +8  (A[m=lane&15][k=quad*8+j] layout, m89-verified)
    bf16x8 afrag[4][4];
    #pragma unroll
    for (int u = 0; u < 4; ++u)
        #pragma unroll
        for (int s = 0; s < 4; ++s)
            afrag[u][s] = *(const bf16x8*)(znb + (size_t)(iw + u * 16 + m) * D + s * 32 + quad * 8);

    // meta for this lane's 16 C-row slots: i = iw + u*16 + quad*4 + r
    int mi[16];
    #pragma unroll
    for (int u = 0; u < 4; ++u)
        #pragma unroll
        for (int r = 0; r < 4; ++r)
            mi[u * 4 + r] = meta[iw + u * 16 + quad * 4 + r];

    unsigned bp[16], bn[16];
    #pragma unroll
    for (int s = 0; s < 16; ++s) { bp[s] = 0xFFFFFFFFu; bn[s] = 0u; }

    for (int t = 0; t < CHUNKJ / 64; ++t) {
        const int jt = jbase + t * 64;

        f32x4 acc[4][4];
        #pragma unroll
        for (int u = 0; u < 4; ++u)
            #pragma unroll
            for (int v = 0; v < 4; ++v)
                acc[u][v] = (f32x4){0.f, 0.f, 0.f, 0.f};

        #pragma unroll
        for (int s = 0; s < 4; ++s) {
            bf16x8 bf[4];
            #pragma unroll
            for (int v = 0; v < 4; ++v)
                bf[v] = *(const bf16x8*)(znb + (size_t)(jt + v * 16 + m) * D + s * 32 + quad * 8);
            #pragma unroll
            for (int u = 0; u < 4; ++u)
                #pragma unroll
                for (int v = 0; v < 4; ++v)
                    acc[u][v] = __builtin_amdgcn_mfma_f32_16x16x32_bf16(afrag[u][s], bf[v], acc[u][v], 0, 0, 0);
        }

        // epilogue: C/D layout col=lane&15, row=quad*4+reg (m89/m91-verified)
        #pragma unroll
        for (int v = 0; v < 4; ++v) {
            const int jv  = jt + v * 16 + m;     // this lane's j for tile v
            const int mjv = meta[jv];
            #pragma unroll
            for (int u = 0; u < 4; ++u)
                #pragma unroll
                for (int r = 0; r < 4; ++r) {
                    float dot = acc[u][v][r];
                    unsigned key = (__float_as_uint(dot + 2.0f) & 0xFFFFE000u) | (unsigned)jv;
                    int x = mi[u * 4 + r] ^ mjv;
                    bool pos = (x != 0) && (x < 32);          // same class, diff subject
                    bool neg = (x != 0) && ((x & 31) == 0);   // diff class, same subject
                    bp[u * 4 + r] = umn(bp[u * 4 + r], pos ? key : 0xFFFFFFFFu);
                    bn[u * 4 + r] = umx(bn[u * 4 + r], neg ? key : 0u);
                }
        }
    }

    // merge across the 16 lanes (different j) sharing each (quad, slot)
    #pragma unroll
    for (int mm = 1; mm < 16; mm <<= 1)
        #pragma unroll
        for (int s = 0; s < 16; ++s) {
            bp[s] = umn(bp[s], (unsigned)__shfl_xor((int)bp[s], mm, 64));
            bn[s] = umx(bn[s], (unsigned)__shfl_xor((int)bn[s], mm, 64));
        }
    if (m == 0) {
        #pragma unroll
        for (int u = 0; u < 4; ++u)
            #pragma unroll
            for (int r = 0; r < 4; ++r) {
                int i = iw + u * 16 + quad * 4 + r;
                posk[(size_t)jc * N + i] = bp[u * 4 + r];
                negk[(size_t)jc * N + i] = bn[u * 4 + r];
            }
    }
}

// ---------------- kernel 3: combine chunks + fp32 hinge ----------------------
__global__ __launch_bounds__(256) void k_final(const float* __restrict__ z,
                                               const float* __restrict__ invn,
                                               const unsigned* __restrict__ posk,
                                               const unsigned* __restrict__ negk,
                                               float* __restrict__ per, float* __restrict__ vld) {
    int row  = blockIdx.x * 4 + (threadIdx.x >> 6);
    int lane = threadIdx.x & 63;
    unsigned mp = 0xFFFFFFFFu, mn = 0u;
    #pragma unroll
    for (int c = 0; c < NCHUNK; ++c) {
        mp = umn(mp, posk[(size_t)c * N + row]);
        mn = umx(mn, negk[(size_t)c * N + row]);
    }
    bool valid = (mp != 0xFFFFFFFFu) && (mn != 0u);
    int pi = valid ? (int)(mp & 8191u) : 0;
    int ni = valid ? (int)(mn & 8191u) : 0;
    float ia = invn[row], ip = invn[pi], iq = invn[ni];
    float2 a = ((const float2*)(z + (size_t)row * D))[lane];
    float2 p = ((const float2*)(z + (size_t)pi  * D))[lane];
    float2 q = ((const float2*)(z + (size_t)ni  * D))[lane];
    float dx = a.x * ia - p.x * ip + PD_EPS, dy = a.y * ia - p.y * ip + PD_EPS;
    float sap = dx * dx + dy * dy;
    dx = a.x * ia - q.x * iq + PD_EPS; dy = a.y * ia - q.y * iq + PD_EPS;
    float san = dx * dx + dy * dy;
    #pragma unroll
    for (int m = 1; m < 64; m <<= 1) {
        sap += __shfl_xor(sap, m, 64);
        san += __shfl_xor(san, m, 64);
    }
    if (lane == 0) {
        float l = fmaxf(sqrtf(sap) - sqrtf(san) + MARGIN, 0.0f);
        per[row] = valid ? l : 0.0f;
        vld[row] = valid ? 1.0f : 0.0f;
    }
}

// ---------------- kernel 4: deterministic final reduce -----------------------
__global__ __launch_bounds__(256) void k_reduce(const float* __restrict__ per,
                                                const float* __restrict__ vld,
                                                float* __restrict__ out) {
    __shared__ float s1[256], s2[256];
    int t = threadIdx.x;
    float a = 0.f, b = 0.f;
    for (int i = t; i < N; i += 256) { a += per[i]; b += vld[i]; }
    s1[t] = a; s2[t] = b;
    __syncthreads();
    for (int w = 128; w > 0; w >>= 1) {
        if (t < w) { s1[t] += s1[t + w]; s2[t] += s2[t + w]; }
        __syncthreads();
    }
    if (t == 0) {
        float cnt = s2[0];
        out[0] = (cnt > 0.f) ? s1[0] / fmaxf(cnt, 1.f) : 0.f;
    }
}

extern "C" void kernel_launch(void* const* d_in, const int* in_sizes, int n_in,
                              void* d_out, int out_size, void* d_ws, size_t ws_size,
                              hipStream_t stream) {
    const float* z        = (const float*)d_in[0];
    const int*   labels   = (const int*)d_in[1];
    const int*   subjects = (const int*)d_in[2];
    float* out = (float*)d_out;

    char* ws = (char*)d_ws;
    unsigned short* znb = (unsigned short*)(ws);            // 2 MB
    float*    invn = (float*)   (ws + 2097152);             // 32 KB
    int*      meta = (int*)     (ws + 2129920);             // 32 KB
    unsigned* posk = (unsigned*)(ws + 2162688);             // 512 KB
    unsigned* negk = (unsigned*)(ws + 2686976);             // 512 KB
    float*    per  = (float*)   (ws + 3211264);             // 32 KB
    float*    vld  = (float*)   (ws + 3244032);             // 32 KB

    k_normalize<<<dim3(N / 4), dim3(256), 0, stream>>>(z, labels, subjects, znb, invn, meta);
    k_mine<<<dim3(32, NCHUNK), dim3(256), 0, stream>>>(znb, meta, posk, negk);
    k_final<<<dim3(N / 4), dim3(256), 0, stream>>>(z, invn, posk, negk, per, vld);
    k_reduce<<<dim3(1), dim3(256), 0, stream>>>(per, vld, out);
}